// Round 9
// baseline (272.310 us; speedup 1.0000x reference)
//
#include <hip/hip_runtime.h>
#include <hip/hip_fp16.h>

static constexpr int F = 64;      // IN_FEATS == HIDDEN
static constexpr int C = 16;      // NUM_CLASSES
static constexpr int EPB = 8192;  // edges per block (hist/partition)
static constexpr int BSH = 9;     // bucket shift: 512 nodes/bucket
static constexpr int SRCB = 17;   // src id bits (nNodes <= 131072)

// -------- prep: features fp32->fp16 (grid-stride) + per-block dst histogram
__global__ void prep(const float* __restrict__ x, __half* __restrict__ xh, int n4,
                     const int* __restrict__ dst, int* __restrict__ bucketCount,
                     int* __restrict__ blockHist, int nEdges) {
    // phase A: convert (independent of phase B)
    int stride = gridDim.x * blockDim.x;
    for (int i = blockIdx.x * blockDim.x + threadIdx.x; i < n4; i += stride) {
        float4 v = ((const float4*)x)[i];
        __half2 p0 = __floats2half2_rn(v.x, v.y);
        __half2 p1 = __floats2half2_rn(v.z, v.w);
        uint2 o;
        o.x = *reinterpret_cast<unsigned*>(&p0);
        o.y = *reinterpret_cast<unsigned*>(&p1);
        ((uint2*)xh)[i] = o;
    }
    // phase B: histogram (proven round-8 body)
    __shared__ int h[256];
    int t = threadIdx.x;
    h[t] = 0;
    __syncthreads();
    int e0 = blockIdx.x * EPB;
    for (int i = 0; i < EPB / 256; ++i) {
        int e = e0 + i * 256 + t;
        if (e < nEdges) atomicAdd(&h[dst[e] >> BSH], 1);
    }
    __syncthreads();
    blockHist[blockIdx.x * 256 + t] = h[t];
    if (h[t]) atomicAdd(&bucketCount[t], h[t]);
}

// ------------------------------- exclusive scan of 256 bucket counts (1 block)
__global__ void bucket_scan(const int* __restrict__ bucketCount,
                            int* __restrict__ bucketStart,
                            int* __restrict__ bucketCursor) {
    __shared__ int s[256];
    int t = threadIdx.x;
    s[t] = bucketCount[t];
    __syncthreads();
    for (int o = 1; o < 256; o <<= 1) {
        int v = (t >= o) ? s[t - o] : 0;
        __syncthreads();
        s[t] += v;
        __syncthreads();
    }
    int ex = (t > 0) ? s[t - 1] : 0;
    bucketStart[t]  = ex;
    bucketCursor[t] = ex;
    if (t == 255) bucketStart[256] = s[255];
}

// ------------- partition edges into bucket-contiguous packed (dloc,src) words
__global__ void partition(const int* __restrict__ src, const int* __restrict__ dst,
                          const int* __restrict__ blockHist,
                          int* __restrict__ bucketCursor, unsigned* __restrict__ pairs,
                          int nEdges) {
    __shared__ int base[256];
    __shared__ int rank[256];
    int t = threadIdx.x;
    rank[t] = 0;
    int c = blockHist[blockIdx.x * 256 + t];
    base[t] = c ? atomicAdd(&bucketCursor[t], c) : 0;  // contiguous slice
    __syncthreads();
    int e0 = blockIdx.x * EPB;
    for (int i = 0; i < EPB / 256; ++i) {
        int e = e0 + i * 256 + t;
        if (e < nEdges) {
            int d = dst[e];
            int b = d >> BSH;
            int r = atomicAdd(&rank[b], 1);
            pairs[base[b] + r] =
                ((unsigned)(d & ((1 << BSH) - 1)) << SRCB) | (unsigned)src[e];
        }
    }
}

// ------- per-bucket: degrees -> local scan -> rowstart + csr (single writer)
__global__ void bucket_csr(const unsigned* __restrict__ pairs,
                           const int* __restrict__ bucketStart,
                           int* __restrict__ rowstart, int* __restrict__ csr,
                           int nNodes, int nEdges) {
    __shared__ int cnt[512];
    __shared__ int s[512];
    __shared__ int cur[512];
    int t = threadIdx.x;
    int b = blockIdx.x;
    int nodeBase = b << BSH;
    int pBeg = bucketStart[b], pEnd = bucketStart[b + 1];
    cnt[t] = 0;
    __syncthreads();
    for (int i = pBeg + t; i < pEnd; i += 512)
        atomicAdd(&cnt[pairs[i] >> SRCB], 1);
    __syncthreads();
    s[t] = cnt[t];
    __syncthreads();
    for (int o = 1; o < 512; o <<= 1) {
        int v = (t >= o) ? s[t - o] : 0;
        __syncthreads();
        s[t] += v;
        __syncthreads();
    }
    int rs = pBeg + ((t > 0) ? s[t - 1] : 0);
    int node = nodeBase + t;
    if (node < nNodes) rowstart[node] = rs;
    cur[t] = rs;
    __syncthreads();
    for (int i = pBeg + t; i < pEnd; i += 512) {
        unsigned p = pairs[i];
        int pos = atomicAdd(&cur[p >> SRCB], 1);
        csr[pos] = (int)(p & ((1u << SRCB) - 1));
    }
    if (b == 0 && t == 0) rowstart[nNodes] = nEdges;
}

// ------------------------------- one fp16 row accumulate (independent chain)
__device__ __forceinline__ void acc_row(float4& a, const uint2* __restrict__ x2,
                                        const int* __restrict__ csr, int k, int q) {
    int s = csr[k];                        // same addr across 16-lane group
    uint2 u = x2[(size_t)s * 16 + q];      // 128B row per group
    __half2 h0 = *reinterpret_cast<__half2*>(&u.x);
    __half2 h1 = *reinterpret_cast<__half2*>(&u.y);
    a.x += __low2float(h0); a.y += __high2float(h0);
    a.z += __low2float(h1); a.w += __high2float(h1);
}

// ------- gather (fp16 rows), 4x unrolled: 16 independent row-chains per wave
__global__ void gather_h(const __half* __restrict__ xh,
                         const int* __restrict__ rowstart,
                         const int* __restrict__ csr,
                         float* __restrict__ agg, int nNodes) {
    __shared__ float4 red[4][4][17];
    int wave = threadIdx.x >> 6, lane = threadIdx.x & 63;
    int node = blockIdx.x * 4 + wave;
    int r = lane >> 4, q = lane & 15;
    int beg = 0, end = 0;
    if (node < nNodes) { beg = rowstart[node]; end = rowstart[node + 1]; }
    const uint2* x2 = (const uint2*)xh;
    float4 a0 = make_float4(0.f, 0.f, 0.f, 0.f);
    float4 a1 = make_float4(0.f, 0.f, 0.f, 0.f);
    float4 a2 = make_float4(0.f, 0.f, 0.f, 0.f);
    float4 a3 = make_float4(0.f, 0.f, 0.f, 0.f);
    for (int kb = beg; kb < end; kb += 16) {   // wave-uniform trip count
        int k0 = kb + r;
        if (k0 < end)      acc_row(a0, x2, csr, k0, q);
        if (k0 + 4 < end)  acc_row(a1, x2, csr, k0 + 4, q);
        if (k0 + 8 < end)  acc_row(a2, x2, csr, k0 + 8, q);
        if (k0 + 12 < end) acc_row(a3, x2, csr, k0 + 12, q);
    }
    float4 acc;
    acc.x = (a0.x + a1.x) + (a2.x + a3.x);
    acc.y = (a0.y + a1.y) + (a2.y + a3.y);
    acc.z = (a0.z + a1.z) + (a2.z + a3.z);
    acc.w = (a0.w + a1.w) + (a2.w + a3.w);
    red[wave][r][q] = acc;
    __syncthreads();                           // block-uniform point
    if (lane < 16 && node < nNodes) {
        float4 a = red[wave][0][lane];
        float4 b = red[wave][1][lane];
        float4 c = red[wave][2][lane];
        float4 d = red[wave][3][lane];
        float inv = 1.0f / fmaxf((float)(end - beg), 1.0f);
        float4 o;
        o.x = (a.x + b.x + c.x + d.x) * inv;
        o.y = (a.y + b.y + c.y + d.y) * inv;
        o.z = (a.z + b.z + c.z + d.z) * inv;
        o.w = (a.w + b.w + c.w + d.w) * inv;
        ((float4*)agg)[(size_t)node * 16 + lane] = o;
    }
}

// ------- dense12: t2 = relu(agg@W1+b1)@W2, 4 nodes/block, LDS-resident
__global__ void dense12(const float* __restrict__ agg, const float* __restrict__ W1,
                        const float* __restrict__ b1, const float* __restrict__ W2,
                        __half* __restrict__ t2, int nNodes) {
    __shared__ float xs[4][F];
    __shared__ float hs[4][F];
    int g = threadIdx.x >> 6, t = threadIdx.x & 63;
    int node = blockIdx.x * 4 + g;
    xs[g][t] = (node < nNodes) ? agg[(size_t)node * F + t] : 0.0f;
    __syncthreads();
    float hacc = b1[t];
#pragma unroll
    for (int k = 0; k < F; ++k) hacc = fmaf(xs[g][k], W1[k * F + t], hacc);
    hs[g][t] = fmaxf(hacc, 0.0f);
    __syncthreads();
    if (t < C && node < nNodes) {
        float o = 0.0f;
#pragma unroll
        for (int k = 0; k < F; ++k) o = fmaf(hs[g][k], W2[k * C + t], o);
        t2[(size_t)node * C + t] = __float2half_rn(o);
    }
}

// ---------- gather16h, 4x unrolled: out = mean_agg(t2) + b2
__global__ void gather16h(const __half* __restrict__ t2,
                          const int* __restrict__ rowstart,
                          const int* __restrict__ csr,
                          const float* __restrict__ b2,
                          float* __restrict__ out, int nNodes) {
    __shared__ float red[4][4][17];
    int wave = threadIdx.x >> 6, lane = threadIdx.x & 63;
    int node = blockIdx.x * 4 + wave;
    int r = lane >> 4, c = lane & 15;
    int beg = 0, end = 0;
    if (node < nNodes) { beg = rowstart[node]; end = rowstart[node + 1]; }
    float a0 = 0.f, a1 = 0.f, a2 = 0.f, a3 = 0.f;
    for (int kb = beg; kb < end; kb += 16) {   // wave-uniform trip count
        int k0 = kb + r;
        if (k0 < end)      a0 += __half2float(t2[(size_t)csr[k0] * C + c]);
        if (k0 + 4 < end)  a1 += __half2float(t2[(size_t)csr[k0 + 4] * C + c]);
        if (k0 + 8 < end)  a2 += __half2float(t2[(size_t)csr[k0 + 8] * C + c]);
        if (k0 + 12 < end) a3 += __half2float(t2[(size_t)csr[k0 + 12] * C + c]);
    }
    red[wave][r][c] = (a0 + a1) + (a2 + a3);
    __syncthreads();                           // block-uniform point
    if (lane < 16 && node < nNodes) {
        float sum = red[wave][0][lane] + red[wave][1][lane]
                  + red[wave][2][lane] + red[wave][3][lane];
        float d = fmaxf((float)(end - beg), 1.0f);
        out[(size_t)node * C + lane] = sum / d + b2[lane];
    }
}

// ---------------------------------------------------------------- launch
extern "C" void kernel_launch(void* const* d_in, const int* in_sizes, int n_in,
                              void* d_out, int out_size, void* d_ws, size_t ws_size,
                              hipStream_t stream) {
    const float* features = (const float*)d_in[0];
    const int*   src      = (const int*)d_in[1];
    const int*   dst      = (const int*)d_in[2];
    const float* W1       = (const float*)d_in[3];
    const float* b1       = (const float*)d_in[4];
    const float* W2       = (const float*)d_in[5];
    const float* b2       = (const float*)d_in[6];
    float*       out      = (float*)d_out;

    const int nNodes = in_sizes[0] / F;           // 100000
    const int nEdges = in_sizes[1];               // 1600000
    const int NBUCK = (nNodes + 511) >> BSH;      // 196 (<= 256)
    const int NBLK  = (nEdges + EPB - 1) / EPB;   // 196

    // ---- workspace carve-up (peak ~48.9 MiB; round-1 proved >=51.6 MiB works)
    char* ws = (char*)d_ws;
    auto align = [](size_t x) { return (x + 255) / 256 * 256; };
    int* bucketCount  = (int*)ws;    ws += align(256 * 4);
    int* bucketStart  = (int*)ws;    ws += align(257 * 4);
    int* bucketCursor = (int*)ws;    ws += align(256 * 4);
    int* blockHist    = (int*)ws;    ws += align((size_t)NBLK * 256 * 4);
    int* rowstart     = (int*)ws;    ws += align((size_t)(nNodes + 1) * 4);
    int* csr          = (int*)ws;    ws += align((size_t)nEdges * 4);
    __half* xh        = (__half*)ws; ws += align((size_t)nNodes * F * 2);
    float* agg        = (float*)ws;  ws += align((size_t)nNodes * F * 4);
    __half* t2h       = (__half*)ws; ws += align((size_t)nNodes * C * 2);
    unsigned* pairs   = (unsigned*)agg;  // 6.4 MB inside agg; dead before gather

    hipMemsetAsync(bucketCount, 0, 256 * sizeof(int), stream);

    // ---- prep (fp16 convert + histogram) then CSR build
    prep<<<NBLK, 256, 0, stream>>>(features, xh, nNodes * F / 4,
                                   dst, bucketCount, blockHist, nEdges);
    bucket_scan<<<1, 256, 0, stream>>>(bucketCount, bucketStart, bucketCursor);
    partition<<<NBLK, 256, 0, stream>>>(src, dst, blockHist, bucketCursor, pairs, nEdges);
    bucket_csr<<<NBUCK, 512, 0, stream>>>(pairs, bucketStart, rowstart, csr,
                                          nNodes, nEdges);

    // ---- layer 1 gather + fused dense (layer1 + W2 pushdown)
    gather_h<<<(nNodes + 3) / 4, 256, 0, stream>>>(xh, rowstart, csr, agg, nNodes);
    dense12<<<(nNodes + 3) / 4, 256, 0, stream>>>(agg, W1, b1, W2, t2h, nNodes);

    // ---- layer 2 aggregation
    gather16h<<<(nNodes + 3) / 4, 256, 0, stream>>>(t2h, rowstart, csr, b2, out, nNodes);
}

// Round 10
// 207.866 us; speedup vs baseline: 1.3100x; 1.3100x over previous
//
#include <hip/hip_runtime.h>
#include <hip/hip_fp16.h>

static constexpr int F = 64;      // IN_FEATS == HIDDEN
static constexpr int C = 16;      // NUM_CLASSES
static constexpr int EPB = 8192;  // edges per block (hist/partition)
static constexpr int BSH = 9;     // bucket shift: 512 nodes/bucket
static constexpr int SRCB = 17;   // src id bits (nNodes <= 131072)

// -------- prep: features fp32->fp16 (grid-stride) + per-block dst histogram
__global__ void prep(const float* __restrict__ x, __half* __restrict__ xh, int n4,
                     const int* __restrict__ dst, int* __restrict__ bucketCount,
                     int* __restrict__ blockHist, int nEdges) {
    int stride = gridDim.x * blockDim.x;
    for (int i = blockIdx.x * blockDim.x + threadIdx.x; i < n4; i += stride) {
        float4 v = ((const float4*)x)[i];
        __half2 p0 = __floats2half2_rn(v.x, v.y);
        __half2 p1 = __floats2half2_rn(v.z, v.w);
        uint2 o;
        o.x = *reinterpret_cast<unsigned*>(&p0);
        o.y = *reinterpret_cast<unsigned*>(&p1);
        ((uint2*)xh)[i] = o;
    }
    __shared__ int h[256];
    int t = threadIdx.x;
    h[t] = 0;
    __syncthreads();
    int e0 = blockIdx.x * EPB;
    for (int i = 0; i < EPB / 256; ++i) {
        int e = e0 + i * 256 + t;
        if (e < nEdges) atomicAdd(&h[dst[e] >> BSH], 1);
    }
    __syncthreads();
    blockHist[blockIdx.x * 256 + t] = h[t];
    if (h[t]) atomicAdd(&bucketCount[t], h[t]);
}

// ------------------------------- exclusive scan of 256 bucket counts (1 block)
__global__ void bucket_scan(const int* __restrict__ bucketCount,
                            int* __restrict__ bucketStart,
                            int* __restrict__ bucketCursor) {
    __shared__ int s[256];
    int t = threadIdx.x;
    s[t] = bucketCount[t];
    __syncthreads();
    for (int o = 1; o < 256; o <<= 1) {
        int v = (t >= o) ? s[t - o] : 0;
        __syncthreads();
        s[t] += v;
        __syncthreads();
    }
    int ex = (t > 0) ? s[t - 1] : 0;
    bucketStart[t]  = ex;
    bucketCursor[t] = ex;
    if (t == 255) bucketStart[256] = s[255];
}

// ------------- partition edges into bucket-contiguous packed (dloc,src) words
__global__ void partition(const int* __restrict__ src, const int* __restrict__ dst,
                          const int* __restrict__ blockHist,
                          int* __restrict__ bucketCursor, unsigned* __restrict__ pairs,
                          int nEdges) {
    __shared__ int base[256];
    __shared__ int rank[256];
    int t = threadIdx.x;
    rank[t] = 0;
    int c = blockHist[blockIdx.x * 256 + t];
    base[t] = c ? atomicAdd(&bucketCursor[t], c) : 0;  // contiguous slice
    __syncthreads();
    int e0 = blockIdx.x * EPB;
    for (int i = 0; i < EPB / 256; ++i) {
        int e = e0 + i * 256 + t;
        if (e < nEdges) {
            int d = dst[e];
            int b = d >> BSH;
            int r = atomicAdd(&rank[b], 1);
            pairs[base[b] + r] =
                ((unsigned)(d & ((1 << BSH) - 1)) << SRCB) | (unsigned)src[e];
        }
    }
}

// ------- per-bucket: degrees -> local scan -> rowstart + csr (single writer)
__global__ void bucket_csr(const unsigned* __restrict__ pairs,
                           const int* __restrict__ bucketStart,
                           int* __restrict__ rowstart, int* __restrict__ csr,
                           int nNodes, int nEdges) {
    __shared__ int cnt[512];
    __shared__ int s[512];
    __shared__ int cur[512];
    int t = threadIdx.x;
    int b = blockIdx.x;
    int nodeBase = b << BSH;
    int pBeg = bucketStart[b], pEnd = bucketStart[b + 1];
    cnt[t] = 0;
    __syncthreads();
    for (int i = pBeg + t; i < pEnd; i += 512)
        atomicAdd(&cnt[pairs[i] >> SRCB], 1);
    __syncthreads();
    s[t] = cnt[t];
    __syncthreads();
    for (int o = 1; o < 512; o <<= 1) {
        int v = (t >= o) ? s[t - o] : 0;
        __syncthreads();
        s[t] += v;
        __syncthreads();
    }
    int rs = pBeg + ((t > 0) ? s[t - 1] : 0);
    int node = nodeBase + t;
    if (node < nNodes) rowstart[node] = rs;
    cur[t] = rs;
    __syncthreads();
    for (int i = pBeg + t; i < pEnd; i += 512) {
        unsigned p = pairs[i];
        int pos = atomicAdd(&cur[p >> SRCB], 1);
        csr[pos] = (int)(p & ((1u << SRCB) - 1));
    }
    if (b == 0 && t == 0) rowstart[nNodes] = nEdges;
}

// ------------------------------- one fp16 row accumulate (independent chain)
__device__ __forceinline__ void acc_row(float4& a, const uint2* __restrict__ x2,
                                        const int* __restrict__ csr, int k, int q) {
    int s = csr[k];                        // same addr across 16-lane group
    uint2 u = x2[(size_t)s * 16 + q];      // 128B row per group
    __half2 h0 = *reinterpret_cast<__half2*>(&u.x);
    __half2 h1 = *reinterpret_cast<__half2*>(&u.y);
    a.x += __low2float(h0); a.y += __high2float(h0);
    a.z += __low2float(h1); a.w += __high2float(h1);
}

// ------- gather (fp16 rows), 4x unrolled (byte-identical to round 9)
__global__ void gather_h(const __half* __restrict__ xh,
                         const int* __restrict__ rowstart,
                         const int* __restrict__ csr,
                         float* __restrict__ agg, int nNodes) {
    __shared__ float4 red[4][4][17];
    int wave = threadIdx.x >> 6, lane = threadIdx.x & 63;
    int node = blockIdx.x * 4 + wave;
    int r = lane >> 4, q = lane & 15;
    int beg = 0, end = 0;
    if (node < nNodes) { beg = rowstart[node]; end = rowstart[node + 1]; }
    const uint2* x2 = (const uint2*)xh;
    float4 a0 = make_float4(0.f, 0.f, 0.f, 0.f);
    float4 a1 = make_float4(0.f, 0.f, 0.f, 0.f);
    float4 a2 = make_float4(0.f, 0.f, 0.f, 0.f);
    float4 a3 = make_float4(0.f, 0.f, 0.f, 0.f);
    for (int kb = beg; kb < end; kb += 16) {   // wave-uniform trip count
        int k0 = kb + r;
        if (k0 < end)      acc_row(a0, x2, csr, k0, q);
        if (k0 + 4 < end)  acc_row(a1, x2, csr, k0 + 4, q);
        if (k0 + 8 < end)  acc_row(a2, x2, csr, k0 + 8, q);
        if (k0 + 12 < end) acc_row(a3, x2, csr, k0 + 12, q);
    }
    float4 acc;
    acc.x = (a0.x + a1.x) + (a2.x + a3.x);
    acc.y = (a0.y + a1.y) + (a2.y + a3.y);
    acc.z = (a0.z + a1.z) + (a2.z + a3.z);
    acc.w = (a0.w + a1.w) + (a2.w + a3.w);
    red[wave][r][q] = acc;
    __syncthreads();                           // block-uniform point
    if (lane < 16 && node < nNodes) {
        float4 a = red[wave][0][lane];
        float4 b = red[wave][1][lane];
        float4 c = red[wave][2][lane];
        float4 d = red[wave][3][lane];
        float inv = 1.0f / fmaxf((float)(end - beg), 1.0f);
        float4 o;
        o.x = (a.x + b.x + c.x + d.x) * inv;
        o.y = (a.y + b.y + c.y + d.y) * inv;
        o.z = (a.z + b.z + c.z + d.z) * inv;
        o.w = (a.w + b.w + c.w + d.w) * inv;
        ((float4*)agg)[(size_t)node * 16 + lane] = o;
    }
}

// ---- dense12_reg: t2 = relu(agg@W1+b1)@W2 with weights held in registers.
// Grid-stride, uniform trip count; W1 column + W2 slice loaded ONCE per thread.
__global__ void dense12_reg(const float* __restrict__ agg,
                            const float* __restrict__ W1,
                            const float* __restrict__ b1,
                            const float* __restrict__ W2,
                            __half* __restrict__ t2, int nNodes) {
    __shared__ float xs[4][F];
    __shared__ float hs[4][F];
    __shared__ float red[4][4][17];
    int wave = threadIdx.x >> 6, lane = threadIdx.x & 63;
    int kk = lane >> 4, c = lane & 15;

    float w1[F];                      // W1 column `lane` (64 VGPRs)
#pragma unroll
    for (int k = 0; k < F; ++k) w1[k] = W1[k * F + lane];
    float b1l = b1[lane];
    float w2[16];                     // W2 rows [kk*16,kk*16+16) of column c
#pragma unroll
    for (int j = 0; j < 16; ++j) w2[j] = W2[(kk * 16 + j) * C + c];

    int step = gridDim.x * 4;
    int start = blockIdx.x * 4 + wave;
    int iters = (nNodes + step - 1) / step;   // uniform across grid
    for (int i = 0; i < iters; ++i) {
        int node = start + i * step;
        bool live = node < nNodes;
        xs[wave][lane] = live ? agg[(size_t)node * F + lane] : 0.0f;
        __syncthreads();
        float hacc = b1l;
#pragma unroll
        for (int k = 0; k < F; ++k) hacc = fmaf(xs[wave][k], w1[k], hacc);
        hs[wave][lane] = fmaxf(hacc, 0.0f);
        __syncthreads();
        float p = 0.0f;
#pragma unroll
        for (int j = 0; j < 16; ++j) p = fmaf(hs[wave][kk * 16 + j], w2[j], p);
        red[wave][kk][c] = p;
        __syncthreads();
        if (lane < C && live) {
            float o = red[wave][0][lane] + red[wave][1][lane]
                    + red[wave][2][lane] + red[wave][3][lane];
            t2[(size_t)node * C + lane] = __float2half_rn(o);
        }
        __syncthreads();   // protect xs/hs/red reuse next iteration
    }
}

// ---------- gather16h, 4x unrolled (byte-identical to round 9)
__global__ void gather16h(const __half* __restrict__ t2,
                          const int* __restrict__ rowstart,
                          const int* __restrict__ csr,
                          const float* __restrict__ b2,
                          float* __restrict__ out, int nNodes) {
    __shared__ float red[4][4][17];
    int wave = threadIdx.x >> 6, lane = threadIdx.x & 63;
    int node = blockIdx.x * 4 + wave;
    int r = lane >> 4, c = lane & 15;
    int beg = 0, end = 0;
    if (node < nNodes) { beg = rowstart[node]; end = rowstart[node + 1]; }
    float a0 = 0.f, a1 = 0.f, a2 = 0.f, a3 = 0.f;
    for (int kb = beg; kb < end; kb += 16) {   // wave-uniform trip count
        int k0 = kb + r;
        if (k0 < end)      a0 += __half2float(t2[(size_t)csr[k0] * C + c]);
        if (k0 + 4 < end)  a1 += __half2float(t2[(size_t)csr[k0 + 4] * C + c]);
        if (k0 + 8 < end)  a2 += __half2float(t2[(size_t)csr[k0 + 8] * C + c]);
        if (k0 + 12 < end) a3 += __half2float(t2[(size_t)csr[k0 + 12] * C + c]);
    }
    red[wave][r][c] = (a0 + a1) + (a2 + a3);
    __syncthreads();                           // block-uniform point
    if (lane < 16 && node < nNodes) {
        float sum = red[wave][0][lane] + red[wave][1][lane]
                  + red[wave][2][lane] + red[wave][3][lane];
        float d = fmaxf((float)(end - beg), 1.0f);
        out[(size_t)node * C + lane] = sum / d + b2[lane];
    }
}

// ---------------------------------------------------------------- launch
extern "C" void kernel_launch(void* const* d_in, const int* in_sizes, int n_in,
                              void* d_out, int out_size, void* d_ws, size_t ws_size,
                              hipStream_t stream) {
    const float* features = (const float*)d_in[0];
    const int*   src      = (const int*)d_in[1];
    const int*   dst      = (const int*)d_in[2];
    const float* W1       = (const float*)d_in[3];
    const float* b1       = (const float*)d_in[4];
    const float* W2       = (const float*)d_in[5];
    const float* b2       = (const float*)d_in[6];
    float*       out      = (float*)d_out;

    const int nNodes = in_sizes[0] / F;           // 100000
    const int nEdges = in_sizes[1];               // 1600000
    const int NBUCK = (nNodes + 511) >> BSH;      // 196 (<= 256)
    const int NBLK  = (nEdges + EPB - 1) / EPB;   // 196

    // ---- workspace carve-up (peak ~48.9 MiB; round-1 proved >=51.6 MiB works)
    char* ws = (char*)d_ws;
    auto align = [](size_t x) { return (x + 255) / 256 * 256; };
    int* bucketCount  = (int*)ws;    ws += align(256 * 4);
    int* bucketStart  = (int*)ws;    ws += align(257 * 4);
    int* bucketCursor = (int*)ws;    ws += align(256 * 4);
    int* blockHist    = (int*)ws;    ws += align((size_t)NBLK * 256 * 4);
    int* rowstart     = (int*)ws;    ws += align((size_t)(nNodes + 1) * 4);
    int* csr          = (int*)ws;    ws += align((size_t)nEdges * 4);
    __half* xh        = (__half*)ws; ws += align((size_t)nNodes * F * 2);
    float* agg        = (float*)ws;  ws += align((size_t)nNodes * F * 4);
    __half* t2h       = (__half*)ws; ws += align((size_t)nNodes * C * 2);
    unsigned* pairs   = (unsigned*)agg;  // 6.4 MB inside agg; dead before gather

    hipMemsetAsync(bucketCount, 0, 256 * sizeof(int), stream);

    // ---- prep (fp16 convert + histogram) then CSR build
    prep<<<NBLK, 256, 0, stream>>>(features, xh, nNodes * F / 4,
                                   dst, bucketCount, blockHist, nEdges);
    bucket_scan<<<1, 256, 0, stream>>>(bucketCount, bucketStart, bucketCursor);
    partition<<<NBLK, 256, 0, stream>>>(src, dst, blockHist, bucketCursor, pairs, nEdges);
    bucket_csr<<<NBUCK, 512, 0, stream>>>(pairs, bucketStart, rowstart, csr,
                                          nNodes, nEdges);

    // ---- layer 1 gather + register-resident dense (layer1 + W2 pushdown)
    gather_h<<<(nNodes + 3) / 4, 256, 0, stream>>>(xh, rowstart, csr, agg, nNodes);
    dense12_reg<<<1024, 256, 0, stream>>>(agg, W1, b1, W2, t2h, nNodes);

    // ---- layer 2 aggregation
    gather16h<<<(nNodes + 3) / 4, 256, 0, stream>>>(t2h, rowstart, csr, b2, out, nNodes);
}

// Round 11
// 165.017 us; speedup vs baseline: 1.6502x; 1.2597x over previous
//
#include <hip/hip_runtime.h>
#include <hip/hip_fp16.h>

static constexpr int F = 64;      // IN_FEATS == HIDDEN
static constexpr int C = 16;      // NUM_CLASSES
static constexpr int EPB = 2048;  // edges per block (hist/partition)
static constexpr int BSH = 9;     // bucket shift: 512 nodes/bucket
static constexpr int SRCB = 17;   // src id bits (nNodes <= 131072)
static constexpr int NPG = 4;     // nodes per 16-lane group (gathers)

// -------- prep: features fp32->fp16 (grid-stride) + per-block dst histogram
__global__ void prep(const float* __restrict__ x, __half* __restrict__ xh, int n4,
                     const int* __restrict__ dst, int* __restrict__ bucketCount,
                     int* __restrict__ blockHist, int nEdges) {
    int stride = gridDim.x * blockDim.x;
    for (int i = blockIdx.x * blockDim.x + threadIdx.x; i < n4; i += stride) {
        float4 v = ((const float4*)x)[i];
        __half2 p0 = __floats2half2_rn(v.x, v.y);
        __half2 p1 = __floats2half2_rn(v.z, v.w);
        uint2 o;
        o.x = *reinterpret_cast<unsigned*>(&p0);
        o.y = *reinterpret_cast<unsigned*>(&p1);
        ((uint2*)xh)[i] = o;
    }
    __shared__ int h[256];
    int t = threadIdx.x;
    h[t] = 0;
    __syncthreads();
    int e0 = blockIdx.x * EPB;
    for (int i = 0; i < EPB / 256; ++i) {
        int e = e0 + i * 256 + t;
        if (e < nEdges) atomicAdd(&h[dst[e] >> BSH], 1);
    }
    __syncthreads();
    blockHist[blockIdx.x * 256 + t] = h[t];
    if (h[t]) atomicAdd(&bucketCount[t], h[t]);
}

// ------------------------------- exclusive scan of 256 bucket counts (1 block)
__global__ void bucket_scan(const int* __restrict__ bucketCount,
                            int* __restrict__ bucketStart,
                            int* __restrict__ bucketCursor) {
    __shared__ int s[256];
    int t = threadIdx.x;
    s[t] = bucketCount[t];
    __syncthreads();
    for (int o = 1; o < 256; o <<= 1) {
        int v = (t >= o) ? s[t - o] : 0;
        __syncthreads();
        s[t] += v;
        __syncthreads();
    }
    int ex = (t > 0) ? s[t - 1] : 0;
    bucketStart[t]  = ex;
    bucketCursor[t] = ex;
    if (t == 255) bucketStart[256] = s[255];
}

// ------------- partition edges into bucket-contiguous packed (dloc,src) words
__global__ void partition(const int* __restrict__ src, const int* __restrict__ dst,
                          const int* __restrict__ blockHist,
                          int* __restrict__ bucketCursor, unsigned* __restrict__ pairs,
                          int nEdges) {
    __shared__ int base[256];
    __shared__ int rank[256];
    int t = threadIdx.x;
    rank[t] = 0;
    int c = blockHist[blockIdx.x * 256 + t];
    base[t] = c ? atomicAdd(&bucketCursor[t], c) : 0;  // contiguous slice
    __syncthreads();
    int e0 = blockIdx.x * EPB;
    for (int i = 0; i < EPB / 256; ++i) {
        int e = e0 + i * 256 + t;
        if (e < nEdges) {
            int d = dst[e];
            int b = d >> BSH;
            int r = atomicAdd(&rank[b], 1);
            pairs[base[b] + r] =
                ((unsigned)(d & ((1 << BSH) - 1)) << SRCB) | (unsigned)src[e];
        }
    }
}

// ------- per-bucket: degrees -> local scan -> rowstart + csr (single writer)
__global__ void bucket_csr(const unsigned* __restrict__ pairs,
                           const int* __restrict__ bucketStart,
                           int* __restrict__ rowstart, int* __restrict__ csr,
                           int nNodes, int nEdges) {
    __shared__ int cnt[512];
    __shared__ int s[512];
    __shared__ int cur[512];
    int t = threadIdx.x;
    int b = blockIdx.x;
    int nodeBase = b << BSH;
    int pBeg = bucketStart[b], pEnd = bucketStart[b + 1];
    cnt[t] = 0;
    __syncthreads();
    for (int i = pBeg + t; i < pEnd; i += 512)
        atomicAdd(&cnt[pairs[i] >> SRCB], 1);
    __syncthreads();
    s[t] = cnt[t];
    __syncthreads();
    for (int o = 1; o < 512; o <<= 1) {
        int v = (t >= o) ? s[t - o] : 0;
        __syncthreads();
        s[t] += v;
        __syncthreads();
    }
    int rs = pBeg + ((t > 0) ? s[t - 1] : 0);
    int node = nodeBase + t;
    if (node < nNodes) rowstart[node] = rs;
    cur[t] = rs;
    __syncthreads();
    for (int i = pBeg + t; i < pEnd; i += 512) {
        unsigned p = pairs[i];
        int pos = atomicAdd(&cur[p >> SRCB], 1);
        csr[pos] = (int)(p & ((1u << SRCB) - 1));
    }
    if (b == 0 && t == 0) rowstart[nNodes] = nEdges;
}

// ---- gather_h2: 16-lane group owns NPG consecutive nodes; lane q = col slice q.
// No LDS, no barriers, contiguous csr stream per group, 4-deep row chains.
__global__ void gather_h2(const __half* __restrict__ xh,
                          const int* __restrict__ rowstart,
                          const int* __restrict__ csr,
                          float* __restrict__ agg, int nNodes) {
    int gid = (blockIdx.x * blockDim.x + threadIdx.x) >> 4;
    int q = threadIdx.x & 15;
    int nodeBase = gid * NPG;
    if (nodeBase >= nNodes) return;
    const uint2* x2 = (const uint2*)xh;
    int rs[NPG + 1];
#pragma unroll
    for (int i = 0; i <= NPG; ++i) rs[i] = rowstart[min(nodeBase + i, nNodes)];
#pragma unroll
    for (int i = 0; i < NPG; ++i) {
        int node = nodeBase + i;
        if (node >= nNodes) break;
        int beg = rs[i], end = rs[i + 1];
        float4 a0 = make_float4(0.f, 0.f, 0.f, 0.f);
        float4 a1 = make_float4(0.f, 0.f, 0.f, 0.f);
        float4 a2 = make_float4(0.f, 0.f, 0.f, 0.f);
        float4 a3 = make_float4(0.f, 0.f, 0.f, 0.f);
        int k = beg;
        for (; k + 4 <= end; k += 4) {   // 4 independent row chains
            int s0 = csr[k], s1 = csr[k + 1], s2 = csr[k + 2], s3 = csr[k + 3];
            uint2 u0 = x2[(size_t)s0 * 16 + q];
            uint2 u1 = x2[(size_t)s1 * 16 + q];
            uint2 u2 = x2[(size_t)s2 * 16 + q];
            uint2 u3 = x2[(size_t)s3 * 16 + q];
            __half2 h00 = *reinterpret_cast<__half2*>(&u0.x);
            __half2 h01 = *reinterpret_cast<__half2*>(&u0.y);
            a0.x += __low2float(h00); a0.y += __high2float(h00);
            a0.z += __low2float(h01); a0.w += __high2float(h01);
            __half2 h10 = *reinterpret_cast<__half2*>(&u1.x);
            __half2 h11 = *reinterpret_cast<__half2*>(&u1.y);
            a1.x += __low2float(h10); a1.y += __high2float(h10);
            a1.z += __low2float(h11); a1.w += __high2float(h11);
            __half2 h20 = *reinterpret_cast<__half2*>(&u2.x);
            __half2 h21 = *reinterpret_cast<__half2*>(&u2.y);
            a2.x += __low2float(h20); a2.y += __high2float(h20);
            a2.z += __low2float(h21); a2.w += __high2float(h21);
            __half2 h30 = *reinterpret_cast<__half2*>(&u3.x);
            __half2 h31 = *reinterpret_cast<__half2*>(&u3.y);
            a3.x += __low2float(h30); a3.y += __high2float(h30);
            a3.z += __low2float(h31); a3.w += __high2float(h31);
        }
        for (; k < end; ++k) {           // tail
            int s0 = csr[k];
            uint2 u0 = x2[(size_t)s0 * 16 + q];
            __half2 h00 = *reinterpret_cast<__half2*>(&u0.x);
            __half2 h01 = *reinterpret_cast<__half2*>(&u0.y);
            a0.x += __low2float(h00); a0.y += __high2float(h00);
            a0.z += __low2float(h01); a0.w += __high2float(h01);
        }
        float inv = 1.0f / fmaxf((float)(end - beg), 1.0f);
        float4 o;
        o.x = ((a0.x + a1.x) + (a2.x + a3.x)) * inv;
        o.y = ((a0.y + a1.y) + (a2.y + a3.y)) * inv;
        o.z = ((a0.z + a1.z) + (a2.z + a3.z)) * inv;
        o.w = ((a0.w + a1.w) + (a2.w + a3.w)) * inv;
        ((float4*)agg)[(size_t)node * 16 + q] = o;   // 256B coalesced per node
    }
}

// ---- dense12_reg: t2 = relu(agg@W1+b1)@W2, weights in registers (round 10)
__global__ void dense12_reg(const float* __restrict__ agg,
                            const float* __restrict__ W1,
                            const float* __restrict__ b1,
                            const float* __restrict__ W2,
                            __half* __restrict__ t2, int nNodes) {
    __shared__ float xs[4][F];
    __shared__ float hs[4][F];
    __shared__ float red[4][4][17];
    int wave = threadIdx.x >> 6, lane = threadIdx.x & 63;
    int kk = lane >> 4, c = lane & 15;

    float w1[F];
#pragma unroll
    for (int k = 0; k < F; ++k) w1[k] = W1[k * F + lane];
    float b1l = b1[lane];
    float w2[16];
#pragma unroll
    for (int j = 0; j < 16; ++j) w2[j] = W2[(kk * 16 + j) * C + c];

    int step = gridDim.x * 4;
    int start = blockIdx.x * 4 + wave;
    int iters = (nNodes + step - 1) / step;
    for (int i = 0; i < iters; ++i) {
        int node = start + i * step;
        bool live = node < nNodes;
        xs[wave][lane] = live ? agg[(size_t)node * F + lane] : 0.0f;
        __syncthreads();
        float hacc = b1l;
#pragma unroll
        for (int k = 0; k < F; ++k) hacc = fmaf(xs[wave][k], w1[k], hacc);
        hs[wave][lane] = fmaxf(hacc, 0.0f);
        __syncthreads();
        float p = 0.0f;
#pragma unroll
        for (int j = 0; j < 16; ++j) p = fmaf(hs[wave][kk * 16 + j], w2[j], p);
        red[wave][kk][c] = p;
        __syncthreads();
        if (lane < C && live) {
            float o = red[wave][0][lane] + red[wave][1][lane]
                    + red[wave][2][lane] + red[wave][3][lane];
            t2[(size_t)node * C + lane] = __float2half_rn(o);
        }
        __syncthreads();
    }
}

// ---- gather16c: layer-2 aggregation, same long-lived group structure
__global__ void gather16c(const __half* __restrict__ t2,
                          const int* __restrict__ rowstart,
                          const int* __restrict__ csr,
                          const float* __restrict__ b2,
                          float* __restrict__ out, int nNodes) {
    int gid = (blockIdx.x * blockDim.x + threadIdx.x) >> 4;
    int c = threadIdx.x & 15;
    int nodeBase = gid * NPG;
    if (nodeBase >= nNodes) return;
    float b2c = b2[c];
    int rs[NPG + 1];
#pragma unroll
    for (int i = 0; i <= NPG; ++i) rs[i] = rowstart[min(nodeBase + i, nNodes)];
#pragma unroll
    for (int i = 0; i < NPG; ++i) {
        int node = nodeBase + i;
        if (node >= nNodes) break;
        int beg = rs[i], end = rs[i + 1];
        float a0 = 0.f, a1 = 0.f, a2 = 0.f, a3 = 0.f;
        int k = beg;
        for (; k + 4 <= end; k += 4) {
            int s0 = csr[k], s1 = csr[k + 1], s2 = csr[k + 2], s3 = csr[k + 3];
            a0 += __half2float(t2[(size_t)s0 * C + c]);
            a1 += __half2float(t2[(size_t)s1 * C + c]);
            a2 += __half2float(t2[(size_t)s2 * C + c]);
            a3 += __half2float(t2[(size_t)s3 * C + c]);
        }
        for (; k < end; ++k) a0 += __half2float(t2[(size_t)csr[k] * C + c]);
        float d = fmaxf((float)(end - beg), 1.0f);
        out[(size_t)node * C + c] = ((a0 + a1) + (a2 + a3)) / d + b2c;
    }
}

// ---------------------------------------------------------------- launch
extern "C" void kernel_launch(void* const* d_in, const int* in_sizes, int n_in,
                              void* d_out, int out_size, void* d_ws, size_t ws_size,
                              hipStream_t stream) {
    const float* features = (const float*)d_in[0];
    const int*   src      = (const int*)d_in[1];
    const int*   dst      = (const int*)d_in[2];
    const float* W1       = (const float*)d_in[3];
    const float* b1       = (const float*)d_in[4];
    const float* W2       = (const float*)d_in[5];
    const float* b2       = (const float*)d_in[6];
    float*       out      = (float*)d_out;

    const int nNodes = in_sizes[0] / F;           // 100000
    const int nEdges = in_sizes[1];               // 1600000
    const int NBUCK = (nNodes + 511) >> BSH;      // 196 (<= 256)
    const int NBLK  = (nEdges + EPB - 1) / EPB;   // 782

    // ---- workspace carve-up (peak ~49.7 MiB; round-1 proved >=51.6 MiB works)
    char* ws = (char*)d_ws;
    auto align = [](size_t x) { return (x + 255) / 256 * 256; };
    int* bucketCount  = (int*)ws;    ws += align(256 * 4);
    int* bucketStart  = (int*)ws;    ws += align(257 * 4);
    int* bucketCursor = (int*)ws;    ws += align(256 * 4);
    int* blockHist    = (int*)ws;    ws += align((size_t)NBLK * 256 * 4);
    int* rowstart     = (int*)ws;    ws += align((size_t)(nNodes + 1) * 4);
    int* csr          = (int*)ws;    ws += align((size_t)nEdges * 4);
    __half* xh        = (__half*)ws; ws += align((size_t)nNodes * F * 2);
    float* agg        = (float*)ws;  ws += align((size_t)nNodes * F * 4);
    __half* t2h       = (__half*)ws; ws += align((size_t)nNodes * C * 2);
    unsigned* pairs   = (unsigned*)agg;  // 6.4 MB inside agg; dead before gather

    hipMemsetAsync(bucketCount, 0, 256 * sizeof(int), stream);

    // ---- prep (fp16 convert + histogram) then CSR build
    prep<<<NBLK, 256, 0, stream>>>(features, xh, nNodes * F / 4,
                                   dst, bucketCount, blockHist, nEdges);
    bucket_scan<<<1, 256, 0, stream>>>(bucketCount, bucketStart, bucketCursor);
    partition<<<NBLK, 256, 0, stream>>>(src, dst, blockHist, bucketCursor, pairs, nEdges);
    bucket_csr<<<NBUCK, 512, 0, stream>>>(pairs, bucketStart, rowstart, csr,
                                          nNodes, nEdges);

    // ---- layer 1 gather (long-lived groups) + register-resident dense
    {
        int nGroups = (nNodes + NPG - 1) / NPG;            // 25000
        int blocks = (nGroups * 16 + 255) / 256;           // 1563
        gather_h2<<<blocks, 256, 0, stream>>>(xh, rowstart, csr, agg, nNodes);
    }
    dense12_reg<<<1024, 256, 0, stream>>>(agg, W1, b1, W2, t2h, nNodes);

    // ---- layer 2 aggregation (long-lived groups)
    {
        int nGroups = (nNodes + NPG - 1) / NPG;
        int blocks = (nGroups * 16 + 255) / 256;
        gather16c<<<blocks, 256, 0, stream>>>(t2h, rowstart, csr, b2, out, nNodes);
    }
}

// Round 12
// 151.649 us; speedup vs baseline: 1.7957x; 1.0882x over previous
//
#include <hip/hip_runtime.h>
#include <hip/hip_fp16.h>

static constexpr int F = 64;      // IN_FEATS == HIDDEN
static constexpr int C = 16;      // NUM_CLASSES
static constexpr int EPB = 2048;  // edges per block (hist/partition)
static constexpr int BSH = 9;     // bucket shift: 512 nodes/bucket
static constexpr int SRCB = 17;   // src id bits (nNodes <= 131072)
static constexpr int NPG = 4;     // nodes per 16-lane group (gathers)

// -------- prep: fp32->fp16 convert + per-block histogram + SLICE RESERVATION
// blockHist[b*256+t] holds this block's RELATIVE base within bucket t.
__global__ void prep(const float* __restrict__ x, __half* __restrict__ xh, int n4,
                     const int* __restrict__ dst, int* __restrict__ bucketCount,
                     int* __restrict__ blockHist, int nEdges) {
    int stride = gridDim.x * blockDim.x;
    for (int i = blockIdx.x * blockDim.x + threadIdx.x; i < n4; i += stride) {
        float4 v = ((const float4*)x)[i];
        __half2 p0 = __floats2half2_rn(v.x, v.y);
        __half2 p1 = __floats2half2_rn(v.z, v.w);
        uint2 o;
        o.x = *reinterpret_cast<unsigned*>(&p0);
        o.y = *reinterpret_cast<unsigned*>(&p1);
        ((uint2*)xh)[i] = o;
    }
    __shared__ int h[256];
    int t = threadIdx.x;
    h[t] = 0;
    __syncthreads();
    int e0 = blockIdx.x * EPB;
    for (int i = 0; i < EPB / 256; ++i) {
        int e = e0 + i * 256 + t;
        if (e < nEdges) atomicAdd(&h[dst[e] >> BSH], 1);
    }
    __syncthreads();
    // reserve this block's contiguous slice in bucket t (relative offset)
    blockHist[blockIdx.x * 256 + t] = h[t] ? atomicAdd(&bucketCount[t], h[t]) : 0;
}

// ------------------------------- exclusive scan of 256 bucket counts (1 block)
__global__ void bucket_scan(const int* __restrict__ bucketCount,
                            int* __restrict__ bucketStart) {
    __shared__ int s[256];
    int t = threadIdx.x;
    s[t] = bucketCount[t];
    __syncthreads();
    for (int o = 1; o < 256; o <<= 1) {
        int v = (t >= o) ? s[t - o] : 0;
        __syncthreads();
        s[t] += v;
        __syncthreads();
    }
    bucketStart[t] = (t > 0) ? s[t - 1] : 0;
    if (t == 255) bucketStart[256] = s[255];
}

// ------------- partition: place edges into pre-reserved bucket slices
__global__ void partition(const int* __restrict__ src, const int* __restrict__ dst,
                          const int* __restrict__ blockHist,
                          const int* __restrict__ bucketStart,
                          unsigned* __restrict__ pairs, int nEdges) {
    __shared__ int base[256];
    __shared__ int rank[256];
    int t = threadIdx.x;
    rank[t] = 0;
    base[t] = bucketStart[t] + blockHist[blockIdx.x * 256 + t];
    __syncthreads();
    int e0 = blockIdx.x * EPB;
    for (int i = 0; i < EPB / 256; ++i) {
        int e = e0 + i * 256 + t;
        if (e < nEdges) {
            int d = dst[e];
            int b = d >> BSH;
            int r = atomicAdd(&rank[b], 1);
            pairs[base[b] + r] =
                ((unsigned)(d & ((1 << BSH) - 1)) << SRCB) | (unsigned)src[e];
        }
    }
}

// ------- per-bucket: degrees -> local scan -> rowstart + csr (single writer)
__global__ void bucket_csr(const unsigned* __restrict__ pairs,
                           const int* __restrict__ bucketStart,
                           int* __restrict__ rowstart, int* __restrict__ csr,
                           int nNodes, int nEdges) {
    __shared__ int cnt[512];
    __shared__ int s[512];
    __shared__ int cur[512];
    int t = threadIdx.x;
    int b = blockIdx.x;
    int nodeBase = b << BSH;
    int pBeg = bucketStart[b], pEnd = bucketStart[b + 1];
    cnt[t] = 0;
    __syncthreads();
    for (int i = pBeg + t; i < pEnd; i += 512)
        atomicAdd(&cnt[pairs[i] >> SRCB], 1);
    __syncthreads();
    s[t] = cnt[t];
    __syncthreads();
    for (int o = 1; o < 512; o <<= 1) {
        int v = (t >= o) ? s[t - o] : 0;
        __syncthreads();
        s[t] += v;
        __syncthreads();
    }
    int rs = pBeg + ((t > 0) ? s[t - 1] : 0);
    int node = nodeBase + t;
    if (node < nNodes) rowstart[node] = rs;
    cur[t] = rs;
    __syncthreads();
    for (int i = pBeg + t; i < pEnd; i += 512) {
        unsigned p = pairs[i];
        int pos = atomicAdd(&cur[p >> SRCB], 1);
        csr[pos] = (int)(p & ((1u << SRCB) - 1));
    }
    if (b == 0 && t == 0) rowstart[nNodes] = nEdges;
}

// ---- gather_h2: 16-lane group owns NPG consecutive nodes (round 11, proven)
__global__ void gather_h2(const __half* __restrict__ xh,
                          const int* __restrict__ rowstart,
                          const int* __restrict__ csr,
                          float* __restrict__ agg, int nNodes) {
    int gid = (blockIdx.x * blockDim.x + threadIdx.x) >> 4;
    int q = threadIdx.x & 15;
    int nodeBase = gid * NPG;
    if (nodeBase >= nNodes) return;
    const uint2* x2 = (const uint2*)xh;
    int rs[NPG + 1];
#pragma unroll
    for (int i = 0; i <= NPG; ++i) rs[i] = rowstart[min(nodeBase + i, nNodes)];
#pragma unroll
    for (int i = 0; i < NPG; ++i) {
        int node = nodeBase + i;
        if (node >= nNodes) break;
        int beg = rs[i], end = rs[i + 1];
        float4 a0 = make_float4(0.f, 0.f, 0.f, 0.f);
        float4 a1 = make_float4(0.f, 0.f, 0.f, 0.f);
        float4 a2 = make_float4(0.f, 0.f, 0.f, 0.f);
        float4 a3 = make_float4(0.f, 0.f, 0.f, 0.f);
        int k = beg;
        for (; k + 4 <= end; k += 4) {   // 4 independent row chains
            int s0 = csr[k], s1 = csr[k + 1], s2 = csr[k + 2], s3 = csr[k + 3];
            uint2 u0 = x2[(size_t)s0 * 16 + q];
            uint2 u1 = x2[(size_t)s1 * 16 + q];
            uint2 u2 = x2[(size_t)s2 * 16 + q];
            uint2 u3 = x2[(size_t)s3 * 16 + q];
            __half2 h00 = *reinterpret_cast<__half2*>(&u0.x);
            __half2 h01 = *reinterpret_cast<__half2*>(&u0.y);
            a0.x += __low2float(h00); a0.y += __high2float(h00);
            a0.z += __low2float(h01); a0.w += __high2float(h01);
            __half2 h10 = *reinterpret_cast<__half2*>(&u1.x);
            __half2 h11 = *reinterpret_cast<__half2*>(&u1.y);
            a1.x += __low2float(h10); a1.y += __high2float(h10);
            a1.z += __low2float(h11); a1.w += __high2float(h11);
            __half2 h20 = *reinterpret_cast<__half2*>(&u2.x);
            __half2 h21 = *reinterpret_cast<__half2*>(&u2.y);
            a2.x += __low2float(h20); a2.y += __high2float(h20);
            a2.z += __low2float(h21); a2.w += __high2float(h21);
            __half2 h30 = *reinterpret_cast<__half2*>(&u3.x);
            __half2 h31 = *reinterpret_cast<__half2*>(&u3.y);
            a3.x += __low2float(h30); a3.y += __high2float(h30);
            a3.z += __low2float(h31); a3.w += __high2float(h31);
        }
        for (; k < end; ++k) {           // tail
            int s0 = csr[k];
            uint2 u0 = x2[(size_t)s0 * 16 + q];
            __half2 h00 = *reinterpret_cast<__half2*>(&u0.x);
            __half2 h01 = *reinterpret_cast<__half2*>(&u0.y);
            a0.x += __low2float(h00); a0.y += __high2float(h00);
            a0.z += __low2float(h01); a0.w += __high2float(h01);
        }
        float inv = 1.0f / fmaxf((float)(end - beg), 1.0f);
        float4 o;
        o.x = ((a0.x + a1.x) + (a2.x + a3.x)) * inv;
        o.y = ((a0.y + a1.y) + (a2.y + a3.y)) * inv;
        o.z = ((a0.z + a1.z) + (a2.z + a3.z)) * inv;
        o.w = ((a0.w + a1.w) + (a2.w + a3.w)) * inv;
        ((float4*)agg)[(size_t)node * 16 + q] = o;   // 256B coalesced per node
    }
}

// ---- dense12_reg: t2 = relu(agg@W1+b1)@W2, weights in registers (round 10)
__global__ void dense12_reg(const float* __restrict__ agg,
                            const float* __restrict__ W1,
                            const float* __restrict__ b1,
                            const float* __restrict__ W2,
                            __half* __restrict__ t2, int nNodes) {
    __shared__ float xs[4][F];
    __shared__ float hs[4][F];
    __shared__ float red[4][4][17];
    int wave = threadIdx.x >> 6, lane = threadIdx.x & 63;
    int kk = lane >> 4, c = lane & 15;

    float w1[F];
#pragma unroll
    for (int k = 0; k < F; ++k) w1[k] = W1[k * F + lane];
    float b1l = b1[lane];
    float w2[16];
#pragma unroll
    for (int j = 0; j < 16; ++j) w2[j] = W2[(kk * 16 + j) * C + c];

    int step = gridDim.x * 4;
    int start = blockIdx.x * 4 + wave;
    int iters = (nNodes + step - 1) / step;
    for (int i = 0; i < iters; ++i) {
        int node = start + i * step;
        bool live = node < nNodes;
        xs[wave][lane] = live ? agg[(size_t)node * F + lane] : 0.0f;
        __syncthreads();
        float hacc = b1l;
#pragma unroll
        for (int k = 0; k < F; ++k) hacc = fmaf(xs[wave][k], w1[k], hacc);
        hs[wave][lane] = fmaxf(hacc, 0.0f);
        __syncthreads();
        float p = 0.0f;
#pragma unroll
        for (int j = 0; j < 16; ++j) p = fmaf(hs[wave][kk * 16 + j], w2[j], p);
        red[wave][kk][c] = p;
        __syncthreads();
        if (lane < C && live) {
            float o = red[wave][0][lane] + red[wave][1][lane]
                    + red[wave][2][lane] + red[wave][3][lane];
            t2[(size_t)node * C + lane] = __float2half_rn(o);
        }
        __syncthreads();
    }
}

// ---- gather16c: layer-2 aggregation (round 11, proven)
__global__ void gather16c(const __half* __restrict__ t2,
                          const int* __restrict__ rowstart,
                          const int* __restrict__ csr,
                          const float* __restrict__ b2,
                          float* __restrict__ out, int nNodes) {
    int gid = (blockIdx.x * blockDim.x + threadIdx.x) >> 4;
    int c = threadIdx.x & 15;
    int nodeBase = gid * NPG;
    if (nodeBase >= nNodes) return;
    float b2c = b2[c];
    int rs[NPG + 1];
#pragma unroll
    for (int i = 0; i <= NPG; ++i) rs[i] = rowstart[min(nodeBase + i, nNodes)];
#pragma unroll
    for (int i = 0; i < NPG; ++i) {
        int node = nodeBase + i;
        if (node >= nNodes) break;
        int beg = rs[i], end = rs[i + 1];
        float a0 = 0.f, a1 = 0.f, a2 = 0.f, a3 = 0.f;
        int k = beg;
        for (; k + 4 <= end; k += 4) {
            int s0 = csr[k], s1 = csr[k + 1], s2 = csr[k + 2], s3 = csr[k + 3];
            a0 += __half2float(t2[(size_t)s0 * C + c]);
            a1 += __half2float(t2[(size_t)s1 * C + c]);
            a2 += __half2float(t2[(size_t)s2 * C + c]);
            a3 += __half2float(t2[(size_t)s3 * C + c]);
        }
        for (; k < end; ++k) a0 += __half2float(t2[(size_t)csr[k] * C + c]);
        float d = fmaxf((float)(end - beg), 1.0f);
        out[(size_t)node * C + c] = ((a0 + a1) + (a2 + a3)) / d + b2c;
    }
}

// ---------------------------------------------------------------- launch
extern "C" void kernel_launch(void* const* d_in, const int* in_sizes, int n_in,
                              void* d_out, int out_size, void* d_ws, size_t ws_size,
                              hipStream_t stream) {
    const float* features = (const float*)d_in[0];
    const int*   src      = (const int*)d_in[1];
    const int*   dst      = (const int*)d_in[2];
    const float* W1       = (const float*)d_in[3];
    const float* b1       = (const float*)d_in[4];
    const float* W2       = (const float*)d_in[5];
    const float* b2       = (const float*)d_in[6];
    float*       out      = (float*)d_out;

    const int nNodes = in_sizes[0] / F;           // 100000
    const int nEdges = in_sizes[1];               // 1600000
    const int NBUCK = (nNodes + 511) >> BSH;      // 196 (<= 256)
    const int NBLK  = (nEdges + EPB - 1) / EPB;   // 782

    // ---- workspace carve-up (peak ~49.7 MiB; round-1 proved >=51.6 MiB works)
    char* ws = (char*)d_ws;
    auto align = [](size_t x) { return (x + 255) / 256 * 256; };
    int* bucketCount  = (int*)ws;    ws += align(256 * 4);
    int* bucketStart  = (int*)ws;    ws += align(257 * 4);
    int* blockHist    = (int*)ws;    ws += align((size_t)NBLK * 256 * 4);
    int* rowstart     = (int*)ws;    ws += align((size_t)(nNodes + 1) * 4);
    int* csr          = (int*)ws;    ws += align((size_t)nEdges * 4);
    __half* xh        = (__half*)ws; ws += align((size_t)nNodes * F * 2);
    float* agg        = (float*)ws;  ws += align((size_t)nNodes * F * 4);
    __half* t2h       = (__half*)ws; ws += align((size_t)nNodes * C * 2);
    unsigned* pairs   = (unsigned*)agg;  // 6.4 MB inside agg; dead before gather

    hipMemsetAsync(bucketCount, 0, 256 * sizeof(int), stream);

    // ---- prep (convert + hist + slice reservation) then CSR build
    prep<<<NBLK, 256, 0, stream>>>(features, xh, nNodes * F / 4,
                                   dst, bucketCount, blockHist, nEdges);
    bucket_scan<<<1, 256, 0, stream>>>(bucketCount, bucketStart);
    partition<<<NBLK, 256, 0, stream>>>(src, dst, blockHist, bucketStart, pairs, nEdges);
    bucket_csr<<<NBUCK, 512, 0, stream>>>(pairs, bucketStart, rowstart, csr,
                                          nNodes, nEdges);

    // ---- layer 1 gather (long-lived groups) + register-resident dense
    {
        int nGroups = (nNodes + NPG - 1) / NPG;            // 25000
        int blocks = (nGroups * 16 + 255) / 256;           // 1563
        gather_h2<<<blocks, 256, 0, stream>>>(xh, rowstart, csr, agg, nNodes);
    }
    dense12_reg<<<2048, 256, 0, stream>>>(agg, W1, b1, W2, t2h, nNodes);

    // ---- layer 2 aggregation (long-lived groups)
    {
        int nGroups = (nNodes + NPG - 1) / NPG;
        int blocks = (nGroups * 16 + 255) / 256;
        gather16c<<<blocks, 256, 0, stream>>>(t2h, rowstart, csr, b2, out, nNodes);
    }
}